// Round 1
// 808.693 us; speedup vs baseline: 1.1401x; 1.1401x over previous
//
#include <hip/hip_runtime.h>

typedef short short8 __attribute__((ext_vector_type(8)));
typedef float f32x4 __attribute__((ext_vector_type(4)));
typedef unsigned short u16;
typedef unsigned int u32;

#define Bq 4
#define Sq 4096
#define Hq 16
#define Dq 128
#define CHUNK 1024
#define NCH 4               /* Sq/CHUNK */
#define QT 128              /* q rows per block (8 waves x 16) */
#define KT 64               /* kv rows per tile */
#define HD (Hq*Dq)          /* 2048: row stride in elements */
#define LOG2E 1.44269504088896f
#define SCALE 0.08838834764831845f /* 1/sqrt(128) */
#define SC2 (SCALE*LOG2E)
#define KELEMS ((size_t)Bq*Sq*Hq*Dq)        /* 33554432 */
#define WS_NEED (2*KELEMS*sizeof(u16))      /* 128 MiB: bf16 K + bf16 V^T */

__device__ __forceinline__ u16 f2bf(float f) {
    union { float f; u32 u; } v; v.f = f;
    u32 r = v.u + 0x7fffu + ((v.u >> 16) & 1u);
    return (u16)(r >> 16);
}

__device__ __forceinline__ short8 pack8(float4 x, float4 y) {
    short8 pk;
    pk[0] = (short)f2bf(x.x); pk[1] = (short)f2bf(x.y);
    pk[2] = (short)f2bf(x.z); pk[3] = (short)f2bf(x.w);
    pk[4] = (short)f2bf(y.x); pk[5] = (short)f2bf(y.y);
    pk[6] = (short)f2bf(y.z); pk[7] = (short)f2bf(y.w);
    return pk;
}

/* ---------------- pre-pass 1: K fp32 -> bf16, same layout ---------------- */
__global__ __launch_bounds__(256) void cvt_bf16_kernel(
    const float* __restrict__ in, u16* __restrict__ out)
{
    size_t i = ((size_t)blockIdx.x * 256 + threadIdx.x) * 8;
    float4 x = *(const float4*)(in + i);
    float4 y = *(const float4*)(in + i + 4);
    *(short8*)(out + i) = pack8(x, y);
}

/* ---------------- pre-pass 2: V fp32 [b s h d] -> bf16 V^T [b h n d c] --- */
__global__ __launch_bounds__(256) void vtr_kernel(
    const float* __restrict__ vg, u16* __restrict__ vt)
{
    __shared__ u16 T[64 * 136];         /* [c=64][d=128] padded to 136 */
    const int tid = threadIdx.x;
    const int bid = blockIdx.x;
    const int cb = bid & 15;            /* 64-row c-block within chunk */
    const int h  = (bid >> 4) & 15;
    const int n  = (bid >> 8) & 3;
    const int b  = bid >> 10;
    const size_t srow0 = (size_t)b * Sq + n * CHUNK + cb * 64;
    /* read 64 rows x 128 d, coalesced (2 rows x 512B per instruction) */
    {
        const int rr = tid >> 5;        /* 0..7 */
        const int d0 = (tid & 31) * 4;
        #pragma unroll
        for (int j = 0; j < 8; ++j) {
            const int r = j * 8 + rr;
            const float* src = vg + (srow0 + r) * HD + (size_t)h * Dq + d0;
            float4 x = *(const float4*)src;
            u16* dst = &T[r * 136 + d0];
            dst[0] = f2bf(x.x); dst[1] = f2bf(x.y);
            dst[2] = f2bf(x.z); dst[3] = f2bf(x.w);
        }
    }
    __syncthreads();
    /* write transposed: row d (128), 64 contiguous c */
    {
        const int c8 = tid & 7;
        const int dd = tid >> 3;        /* 0..31 */
        const size_t obase = ((size_t)(b * Hq + h) * NCH + n) * Dq;
        #pragma unroll
        for (int j = 0; j < 4; ++j) {
            const int d = j * 32 + dd;
            short8 pk;
            #pragma unroll
            for (int e = 0; e < 8; ++e) pk[e] = (short)T[(c8 * 8 + e) * 136 + d];
            *(short8*)(vt + (obase + d) * CHUNK + cb * 64 + c8 * 8) = pk;
        }
    }
}

/* ---------------- main attention kernel (bf16 K / V^T from ws) ----------- */
__global__ __launch_bounds__(512, 4) void attn_sink_bf16_kernel(
    const float* __restrict__ qg, const u16* __restrict__ kb,
    const u16* __restrict__ vt, const float* __restrict__ sg,
    float* __restrict__ og)
{
    /* double-buffered K [64][128] and V^T [128][64], 16B-chunk XOR swizzle */
    __shared__ __align__(16) u16 Ksh[2][KT * Dq];   /* 2 x 16 KB */
    __shared__ __align__(16) u16 Vsh[2][Dq * KT];   /* 2 x 16 KB */
    __shared__ __align__(16) u16 Psh[8][16 * KT];   /* 16 KB, per-wave */

    const int tid  = threadIdx.x;
    const int lane = tid & 63;
    const int wave = tid >> 6;
    const int l16  = lane & 15;
    const int quad = lane >> 4;

    /* XCD-chunked swizzle: 2048 blocks, 8 XCDs -> 256 contiguous per XCD */
    const int bid = (blockIdx.x & 7) * 256 + (blockIdx.x >> 3);
    const int qt  = 7 - (bid & 7);          /* heavy-first */
    const int nch = (bid >> 3) & 3;
    const int h   = (bid >> 5) & 15;
    const int b   = bid >> 9;

    const int s0    = nch * CHUNK;
    const int qrow0 = qt * QT + wave * 16;

    const size_t base   = ((size_t)b * Sq + s0) * HD + (size_t)h * Dq;
    const size_t vtbase = ((size_t)(b * Hq + h) * NCH + nch) * (size_t)Dq * CHUNK;

    /* Q fragments (A-operand): lane = row l16, d = ks*32 + quad*8 .. +7 */
    short8 qf[4];
    {
        const float* qrow = qg + base + (size_t)(qrow0 + l16) * HD + quad * 8;
        #pragma unroll
        for (int ks = 0; ks < 4; ++ks) {
            float4 x = *(const float4*)(qrow + ks * 32);
            float4 y = *(const float4*)(qrow + ks * 32 + 4);
            qf[ks] = pack8(x, y);
        }
    }

    const float sink2 = sg[h] * LOG2E;      /* log2-domain sink */
    float m_r[4], l_r[4];
    f32x4 O[8];
    #pragma unroll
    for (int i = 0; i < 8; ++i) O[i] = (f32x4){0.f, 0.f, 0.f, 0.f};
    #pragma unroll
    for (int r = 0; r < 4; ++r) { m_r[r] = sink2; l_r[r] = 1.0f; }

    /* staging geometry: per wave 8 K rows + 16 V^T rows, two 16B chunks each */
    const int rkl   = lane >> 4;
    const int ck    = lane & 15;
    const int krow0 = wave * 8 + rkl;
    const int krow1 = krow0 + 4;
    const u32 koff0 = krow0 * 256 + ((ck ^ (krow0 & 7)) << 4);
    const u32 koff1 = krow1 * 256 + ((ck ^ (krow1 & 7)) << 4);
    const u16* kg0  = kb + base + (size_t)krow0 * HD + ck * 8;
    const u16* kg1  = kb + base + (size_t)krow1 * HD + ck * 8;

    const int sv    = lane & 7;
    const int dv0   = wave * 16 + (lane >> 3);
    const int dv1   = dv0 + 8;
    const u32 voff0 = dv0 * 128 + ((sv ^ (dv0 & 7)) << 4);
    const u32 voff1 = dv1 * 128 + ((sv ^ (dv1 & 7)) << 4);
    const u16* vg0  = vt + vtbase + (size_t)dv0 * CHUNK + sv * 8;
    const u16* vg1  = vt + vtbase + (size_t)dv1 * CHUNK + sv * 8;

    short8 kr0, kr1, vr0, vr1;
    auto LOADT = [&](int t) {                    /* issue-early (T14) */
        const size_t ko = (size_t)t * KT * HD;
        const int    vo = t * KT;
        kr0 = *(const short8*)(kg0 + ko);
        kr1 = *(const short8*)(kg1 + ko);
        vr0 = *(const short8*)(vg0 + vo);
        vr1 = *(const short8*)(vg1 + vo);
    };
    auto WRITET = [&](int buf) {                 /* write-late */
        char* Kb_ = (char*)Ksh[buf];
        char* Vb_ = (char*)Vsh[buf];
        *(short8*)(Kb_ + koff0) = kr0;
        *(short8*)(Kb_ + koff1) = kr1;
        *(short8*)(Vb_ + voff0) = vr0;
        *(short8*)(Vb_ + voff1) = vr1;
    };

    const int nkv   = 2 * qt + 2;                          /* block tile count */
    const int nkv_w = ((qt * QT + wave * 16 + 15) >> 6) + 1; /* per-wave count */
    u16* Pw = Psh[wave];

    LOADT(0);
    WRITET(0);
    __syncthreads();

    int cur = 0;
    for (int t = 0; t < nkv; ++t) {
        const bool havenext = (t + 1 < nkv);
        LOADT(havenext ? t + 1 : t);            /* unconditional so loads hoist */
        __builtin_amdgcn_sched_barrier(0);      /* pin loads before compute */

        if (t < nkv_w) {
            const u16* Kc = Ksh[cur];
            const u16* Vc = Vsh[cur];
            const int kv0 = t << 6;

            /* S = Q K^T */
            f32x4 Sv[4];
            __builtin_amdgcn_s_setprio(1);
            #pragma unroll
            for (int blk = 0; blk < 4; ++blk) {
                f32x4 acc = (f32x4){0.f, 0.f, 0.f, 0.f};
                #pragma unroll
                for (int ks = 0; ks < 4; ++ks) {
                    const int ch = ((ks << 2) + quad) ^ (l16 & 7);
                    short8 kf = *(const short8*)&Kc[(((blk << 4) + l16) << 7) + (ch << 3)];
                    acc = __builtin_amdgcn_mfma_f32_16x16x32_bf16(qf[ks], kf, acc, 0, 0, 0);
                }
                Sv[blk] = acc;
            }
            __builtin_amdgcn_s_setprio(0);

            /* log2-scale + causal mask (only on diagonal-crossing tiles) */
            const bool domask = (kv0 + KT - 1 > qrow0);
            float s2[4][4];
            #pragma unroll
            for (int blk = 0; blk < 4; ++blk) {
                #pragma unroll
                for (int r = 0; r < 4; ++r) {
                    float x = Sv[blk][r] * SC2;
                    if (domask) {
                        const int col = kv0 + (blk << 4) + l16;
                        const int row = qrow0 + (quad << 2) + r;
                        if (col > row) x = -1.0e38f;
                    }
                    s2[blk][r] = x;
                }
            }

            /* online softmax (log2 domain) */
            float mx[4];
            #pragma unroll
            for (int r = 0; r < 4; ++r)
                mx[r] = fmaxf(fmaxf(s2[0][r], s2[1][r]), fmaxf(s2[2][r], s2[3][r]));
            #pragma unroll
            for (int off = 1; off < 16; off <<= 1)
                #pragma unroll
                for (int r = 0; r < 4; ++r)
                    mx[r] = fmaxf(mx[r], __shfl_xor(mx[r], off, 64));

            float alpha[4], rs[4];
            #pragma unroll
            for (int r = 0; r < 4; ++r) {
                const float mn = fmaxf(m_r[r], mx[r]);
                alpha[r] = exp2f(m_r[r] - mn);
                m_r[r] = mn;
                rs[r] = 0.f;
            }

            /* P = exp2(s2 - m), write to per-wave LDS in A-layout */
            #pragma unroll
            for (int blk = 0; blk < 4; ++blk) {
                const int colhi = (blk << 1) + (l16 >> 3);
                const int collo = l16 & 7;
                #pragma unroll
                for (int r = 0; r < 4; ++r) {
                    const float p = exp2f(s2[blk][r] - m_r[r]);
                    rs[r] += p;
                    const int row = (quad << 2) + r;
                    Pw[(row << 6) + ((colhi ^ (row & 7)) << 3) + collo] = f2bf(p);
                }
            }
            #pragma unroll
            for (int off = 1; off < 16; off <<= 1)
                #pragma unroll
                for (int r = 0; r < 4; ++r)
                    rs[r] += __shfl_xor(rs[r], off, 64);
            #pragma unroll
            for (int r = 0; r < 4; ++r) l_r[r] = l_r[r] * alpha[r] + rs[r];

            #pragma unroll
            for (int ob = 0; ob < 8; ++ob)
                #pragma unroll
                for (int r = 0; r < 4; ++r)
                    O[ob][r] *= alpha[r];

            /* O += P V */
            __builtin_amdgcn_s_setprio(1);
            #pragma unroll
            for (int ks2 = 0; ks2 < 2; ++ks2) {
                const int ch = ((ks2 << 2) + quad) ^ (l16 & 7);
                short8 pf = *(const short8*)&Pw[(l16 << 6) + (ch << 3)];
                #pragma unroll
                for (int ob = 0; ob < 8; ++ob) {
                    short8 vf = *(const short8*)&Vc[(((ob << 4) + l16) << 6) + (ch << 3)];
                    O[ob] = __builtin_amdgcn_mfma_f32_16x16x32_bf16(pf, vf, O[ob], 0, 0, 0);
                }
            }
            __builtin_amdgcn_s_setprio(0);
        }

        if (havenext) WRITET(cur ^ 1);
        __syncthreads();                         /* single barrier per tile */
        cur ^= 1;
    }

    /* epilogue: normalize by l (includes sink term), store fp32 */
    #pragma unroll
    for (int r = 0; r < 4; ++r) l_r[r] = 1.0f / l_r[r];
    #pragma unroll
    for (int ob = 0; ob < 8; ++ob) {
        #pragma unroll
        for (int r = 0; r < 4; ++r) {
            const int row = qrow0 + (quad << 2) + r;
            og[base + (size_t)row * HD + (ob << 4) + l16] = O[ob][r] * l_r[r];
        }
    }
}

/* ---------------- fallback (previous verified kernel, fp32 inputs) ------- */
__global__ __launch_bounds__(256, 3) void attn_sink_kernel(
    const float* __restrict__ qg, const float* __restrict__ kg,
    const float* __restrict__ vg, const float* __restrict__ sg,
    float* __restrict__ og)
{
    __shared__ __align__(16) u16 Ksh[KT * Dq];
    __shared__ __align__(16) u16 Vsh[Dq * KT];
    __shared__ __align__(16) u16 Psh[4][16 * KT];

    const int tid  = threadIdx.x;
    const int lane = tid & 63;
    const int wave = tid >> 6;
    const int l16  = lane & 15;
    const int quad = lane >> 4;

    const int bid = blockIdx.x;
    const int qt  = bid & 15;
    const int nch = (bid >> 4) & 3;
    const int h   = (bid >> 6) & 15;
    const int b   = bid >> 10;

    const int s0    = nch * CHUNK;
    const int qrow0 = qt * 64 + wave * 16;

    const size_t base = ((size_t)b * Sq + s0) * HD + (size_t)h * Dq;

    short8 qf[4];
    {
        const float* qrow = qg + base + (size_t)(qrow0 + l16) * HD + quad * 8;
        #pragma unroll
        for (int ks = 0; ks < 4; ++ks) {
            float4 x = *(const float4*)(qrow + ks * 32);
            float4 y = *(const float4*)(qrow + ks * 32 + 4);
            qf[ks] = pack8(x, y);
        }
    }

    const float sinkv = sg[h];

    float m_r[4], l_r[4];
    f32x4 O[8];
    #pragma unroll
    for (int i = 0; i < 8; ++i) O[i] = (f32x4){0.f, 0.f, 0.f, 0.f};
    #pragma unroll
    for (int r = 0; r < 4; ++r) { m_r[r] = sinkv; l_r[r] = 1.0f; }

    const int nkv = qt + 1;
    for (int t = 0; t < nkv; ++t) {
        const int kv0 = t * KT;
        __syncthreads();

        #pragma unroll
        for (int p = 0; p < 4; ++p) {
            int idx = tid + p * 256;
            int r = idx >> 4, c = idx & 15;
            const float* src = kg + base + (size_t)(kv0 + r) * HD + c * 8;
            float4 x = *(const float4*)src;
            float4 y = *(const float4*)(src + 4);
            *(short8*)&Ksh[(r << 7) + ((c ^ (r & 7)) << 3)] = pack8(x, y);
        }
        {
            int vr = lane;
            int c0 = wave;
            #pragma unroll
            for (int p = 0; p < 4; ++p) {
                int c = c0 + (p << 2);
                const float* src = vg + base + (size_t)(kv0 + vr) * HD + c * 8;
                float4 x = *(const float4*)src;
                float4 y = *(const float4*)(src + 4);
                float vals[8] = {x.x, x.y, x.z, x.w, y.x, y.y, y.z, y.w};
                #pragma unroll
                for (int j = 0; j < 8; ++j) {
                    int d = c * 8 + j;
                    Vsh[(d << 6) + (((vr >> 3) ^ j) << 3) + (vr & 7)] = f2bf(vals[j]);
                }
            }
        }
        __syncthreads();

        f32x4 Sv[4];
        #pragma unroll
        for (int blk = 0; blk < 4; ++blk) {
            f32x4 acc = (f32x4){0.f, 0.f, 0.f, 0.f};
            #pragma unroll
            for (int ks = 0; ks < 4; ++ks) {
                int ch = ((ks << 2) + quad) ^ (l16 & 7);
                short8 kf = *(const short8*)&Ksh[(((blk << 4) + l16) << 7) + (ch << 3)];
                acc = __builtin_amdgcn_mfma_f32_16x16x32_bf16(qf[ks], kf, acc, 0, 0, 0);
            }
            Sv[blk] = acc;
        }

        float s[4][4];
        const bool domask = (t == nkv - 1);
        #pragma unroll
        for (int blk = 0; blk < 4; ++blk) {
            #pragma unroll
            for (int r = 0; r < 4; ++r) {
                float x = Sv[blk][r] * SCALE;
                if (domask) {
                    int col = kv0 + (blk << 4) + l16;
                    int row = qrow0 + (quad << 2) + r;
                    if (col > row) x = -1.0e38f;
                }
                s[blk][r] = x;
            }
        }

        float mx[4];
        #pragma unroll
        for (int r = 0; r < 4; ++r)
            mx[r] = fmaxf(fmaxf(s[0][r], s[1][r]), fmaxf(s[2][r], s[3][r]));
        #pragma unroll
        for (int off = 1; off < 16; off <<= 1)
            #pragma unroll
            for (int r = 0; r < 4; ++r)
                mx[r] = fmaxf(mx[r], __shfl_xor(mx[r], off, 64));

        float mn[4], alpha[4], rs[4];
        #pragma unroll
        for (int r = 0; r < 4; ++r) {
            mn[r] = fmaxf(m_r[r], mx[r]);
            alpha[r] = exp2f((m_r[r] - mn[r]) * LOG2E);
            m_r[r] = mn[r];
            rs[r] = 0.f;
        }

        u16* Pw = Psh[wave];
        #pragma unroll
        for (int blk = 0; blk < 4; ++blk) {
            int colhi = (blk << 1) + (l16 >> 3);
            int collo = l16 & 7;
            #pragma unroll
            for (int r = 0; r < 4; ++r) {
                float p = exp2f((s[blk][r] - mn[r]) * LOG2E);
                rs[r] += p;
                int row = (quad << 2) + r;
                Pw[(row << 6) + ((colhi ^ (row & 7)) << 3) + collo] = f2bf(p);
            }
        }
        #pragma unroll
        for (int off = 1; off < 16; off <<= 1)
            #pragma unroll
            for (int r = 0; r < 4; ++r)
                rs[r] += __shfl_xor(rs[r], off, 64);
        #pragma unroll
        for (int r = 0; r < 4; ++r) l_r[r] = l_r[r] * alpha[r] + rs[r];

        #pragma unroll
        for (int ob = 0; ob < 8; ++ob)
            #pragma unroll
            for (int r = 0; r < 4; ++r)
                O[ob][r] *= alpha[r];

        __syncthreads();

        #pragma unroll
        for (int ks2 = 0; ks2 < 2; ++ks2) {
            int ch = ((ks2 << 2) + quad) ^ (l16 & 7);
            short8 pf = *(const short8*)&Pw[(l16 << 6) + (ch << 3)];
            #pragma unroll
            for (int ob = 0; ob < 8; ++ob) {
                int n = (ob << 4) + l16;
                short8 vf = *(const short8*)&Vsh[(n << 6) + (ch << 3)];
                O[ob] = __builtin_amdgcn_mfma_f32_16x16x32_bf16(pf, vf, O[ob], 0, 0, 0);
            }
        }
    }

    #pragma unroll
    for (int r = 0; r < 4; ++r) l_r[r] = 1.0f / l_r[r];
    #pragma unroll
    for (int ob = 0; ob < 8; ++ob) {
        #pragma unroll
        for (int r = 0; r < 4; ++r) {
            int row = qrow0 + (quad << 2) + r;
            og[base + (size_t)row * HD + (ob << 4) + l16] = O[ob][r] * l_r[r];
        }
    }
}

extern "C" void kernel_launch(void* const* d_in, const int* in_sizes, int n_in,
                              void* d_out, int out_size, void* d_ws, size_t ws_size,
                              hipStream_t stream) {
    const float* q = (const float*)d_in[0];
    const float* k = (const float*)d_in[1];
    const float* v = (const float*)d_in[2];
    const float* s = (const float*)d_in[3];
    float* out = (float*)d_out;

    if (ws_size >= WS_NEED) {
        u16* kb = (u16*)d_ws;
        u16* vt = kb + KELEMS;
        cvt_bf16_kernel<<<dim3((u32)(KELEMS / 8 / 256)), 256, 0, stream>>>(k, kb);
        vtr_kernel<<<dim3(Bq * NCH * Hq * (CHUNK / 64)), 256, 0, stream>>>(v, vt);
        attn_sink_bf16_kernel<<<dim3(Bq * Hq * NCH * (CHUNK / QT)), 512, 0, stream>>>(
            q, kb, vt, s, out);
    } else {
        attn_sink_kernel<<<dim3(Bq * Hq * NCH * (CHUNK / 64)), 256, 0, stream>>>(
            q, k, v, s, out);
    }
}

// Round 2
// 513.979 us; speedup vs baseline: 1.7939x; 1.5734x over previous
//
#include <hip/hip_runtime.h>

typedef short short8 __attribute__((ext_vector_type(8)));
typedef float f32x4 __attribute__((ext_vector_type(4)));
typedef float f32x16 __attribute__((ext_vector_type(16)));
typedef unsigned short u16;
typedef unsigned int u32;

#define Bq 4
#define Sq 4096
#define Hq 16
#define Dq 128
#define CHUNK 1024
#define NCH 4               /* Sq/CHUNK */
#define KT 64               /* kv rows per tile */
#define HD (Hq*Dq)          /* 2048: row stride in elements */
#define LOG2E 1.44269504088896f
#define SCALE 0.08838834764831845f /* 1/sqrt(128) */
#define SC2 (SCALE*LOG2E)
#define THR 5.0f            /* defer-max threshold (log2 domain) */
#define KELEMS ((size_t)Bq*Sq*Hq*Dq)        /* 33554432 */
#define WS_NEED (2*KELEMS*sizeof(u16))      /* 128 MiB: bf16 K + bf16 V^T */

__device__ __forceinline__ u16 f2bf(float f) {
    union { float f; u32 u; } v; v.f = f;
    u32 r = v.u + 0x7fffu + ((v.u >> 16) & 1u);
    return (u16)(r >> 16);
}

__device__ __forceinline__ short8 pack8(float4 x, float4 y) {
    short8 pk;
    pk[0] = (short)f2bf(x.x); pk[1] = (short)f2bf(x.y);
    pk[2] = (short)f2bf(x.z); pk[3] = (short)f2bf(x.w);
    pk[4] = (short)f2bf(y.x); pk[5] = (short)f2bf(y.y);
    pk[6] = (short)f2bf(y.z); pk[7] = (short)f2bf(y.w);
    return pk;
}

/* ---------------- pre-pass 1: K fp32 -> bf16, same layout (coalesced) ---- */
__global__ __launch_bounds__(256) void cvt_bf16_kernel(
    const float* __restrict__ in, u16* __restrict__ out)
{
    const size_t g = (size_t)blockIdx.x * 256 + threadIdx.x;
    const float4 x = ((const float4*)in)[g];
    union { u16 h[4]; uint2 u; } o;
    o.h[0] = f2bf(x.x); o.h[1] = f2bf(x.y);
    o.h[2] = f2bf(x.z); o.h[3] = f2bf(x.w);
    ((uint2*)out)[g] = o.u;
}

/* ---------------- pre-pass 2: V fp32 [b s h d] -> bf16 V^T [b h n d c] --- */
__global__ __launch_bounds__(256) void vtr_kernel(
    const float* __restrict__ vg, u16* __restrict__ vt)
{
    __shared__ u16 T[64 * 136];         /* [c=64][d=128] padded to 136 */
    const int tid = threadIdx.x;
    const int bid = blockIdx.x;
    const int cb = bid & 15;            /* 64-row c-block within chunk */
    const int h  = (bid >> 4) & 15;
    const int n  = (bid >> 8) & 3;
    const int b  = bid >> 10;
    const size_t srow0 = (size_t)b * Sq + n * CHUNK + cb * 64;
    {
        const int rr = tid >> 5;        /* 0..7 */
        const int d0 = (tid & 31) * 4;
        #pragma unroll
        for (int j = 0; j < 8; ++j) {
            const int r = j * 8 + rr;
            const float* src = vg + (srow0 + r) * HD + (size_t)h * Dq + d0;
            float4 x = *(const float4*)src;
            u16* dst = &T[r * 136 + d0];
            dst[0] = f2bf(x.x); dst[1] = f2bf(x.y);
            dst[2] = f2bf(x.z); dst[3] = f2bf(x.w);
        }
    }
    __syncthreads();
    {
        const int c8 = tid & 7;
        const int dd = tid >> 3;        /* 0..31 */
        const size_t obase = ((size_t)(b * Hq + h) * NCH + n) * Dq;
        #pragma unroll
        for (int j = 0; j < 4; ++j) {
            const int d = j * 32 + dd;
            short8 pk;
            #pragma unroll
            for (int e = 0; e < 8; ++e) pk[e] = (short)T[(c8 * 8 + e) * 136 + d];
            *(short8*)(vt + (obase + d) * CHUNK + cb * 64 + c8 * 8) = pk;
        }
    }
}

/* ======================= main attention kernel v2 ========================
 * 8 waves x 32 q-rows (QT=256), swapped QK^T (mfma(K,Q) -> S^T), in-register
 * softmax (lane owns one q row), 32x32x16 MFMA, defer-max, paired q-tiles
 * for uniform block work. K/V bf16 from workspace, double-buffered LDS.
 * ======================================================================== */
__global__ __launch_bounds__(512, 2) void attn_sink_v2(
    const float* __restrict__ qg, const u16* __restrict__ kb,
    const u16* __restrict__ vt, const float* __restrict__ sg,
    float* __restrict__ og)
{
    __shared__ __align__(16) u16 Ksh[2][KT * Dq];   /* 2 x 16 KB, [64][128] */
    __shared__ __align__(16) u16 Vsh[2][Dq * KT];   /* 2 x 16 KB, [128][64] */

    const int tid  = threadIdx.x;
    const int lane = tid & 63;
    const int wave = tid >> 6;
    const int l31  = lane & 31;
    const int hi   = lane >> 5;

    /* XCD-chunked swizzle: 512 blocks, 64 contiguous per XCD */
    const int bid = (blockIdx.x & 7) * 64 + (blockIdx.x >> 3);
    const int pi  = bid & 1;            /* pair index: parts do qt {3-pi, pi} */
    const int nch = (bid >> 1) & 3;
    const int h   = (bid >> 3) & 15;
    const int b   = bid >> 7;

    const int s0 = nch * CHUNK;
    const size_t base   = ((size_t)b * Sq + s0) * HD + (size_t)h * Dq;
    const size_t vtbase = ((size_t)(b * Hq + h) * NCH + nch) * (size_t)Dq * CHUNK;

    const float sink2 = sg[h] * LOG2E;  /* log2-domain sink */

    /* staging geometry: per wave 8 K rows + 16 V^T rows, two 16B chunks each */
    const int rkl   = lane >> 4;
    const int ck    = lane & 15;
    const int krow0 = wave * 8 + rkl;
    const int krow1 = krow0 + 4;
    const u32 koff0 = krow0 * 256 + ((ck ^ (krow0 & 7)) << 4);
    const u32 koff1 = krow1 * 256 + ((ck ^ (krow1 & 7)) << 4);
    const u16* kg0  = kb + base + (size_t)krow0 * HD + ck * 8;
    const u16* kg1  = kb + base + (size_t)krow1 * HD + ck * 8;

    const int sv    = lane & 7;
    const int dv0   = wave * 16 + (lane >> 3);
    const int dv1   = dv0 + 8;
    const u32 voff0 = dv0 * 128 + ((sv ^ (dv0 & 7)) << 4);
    const u32 voff1 = dv1 * 128 + ((sv ^ (dv1 & 7)) << 4);
    const u16* vg0  = vt + vtbase + (size_t)dv0 * CHUNK + sv * 8;
    const u16* vg1  = vt + vtbase + (size_t)dv1 * CHUNK + sv * 8;

    short8 kr0, kr1, vr0, vr1;
    auto LOADT = [&](int t) {                    /* issue-early (T14) */
        const size_t ko = (size_t)t * KT * HD;
        const int    vo = t * KT;
        kr0 = *(const short8*)(kg0 + ko);
        kr1 = *(const short8*)(kg1 + ko);
        vr0 = *(const short8*)(vg0 + vo);
        vr1 = *(const short8*)(vg1 + vo);
    };
    auto WRITET = [&](int buf) {                 /* write-late */
        char* Kb_ = (char*)Ksh[buf];
        char* Vb_ = (char*)Vsh[buf];
        *(short8*)(Kb_ + koff0) = kr0;
        *(short8*)(Kb_ + koff1) = kr1;
        *(short8*)(Vb_ + voff0) = vr0;
        *(short8*)(Vb_ + voff1) = vr1;
    };

    #pragma unroll 1
    for (int part = 0; part < 2; ++part) {
        const int qt = part ? pi : 3 - pi;           /* heavy part first */
        const int qrow0w = qt * 256 + wave * 32;     /* wave's q base in chunk */

        /* ---- Q fragments (B-operand), scale folded in:
         * lane holds Q[q = l31][d = ds*16 + hi*8 + e] * SC2 as bf16 */
        short8 qf[8];
        {
            const float* qrow = qg + base + (size_t)(qrow0w + l31) * HD + hi * 8;
            #pragma unroll
            for (int ds = 0; ds < 8; ++ds) {
                float4 x = *(const float4*)(qrow + ds * 16);
                float4 y = *(const float4*)(qrow + ds * 16 + 4);
                x.x *= SC2; x.y *= SC2; x.z *= SC2; x.w *= SC2;
                y.x *= SC2; y.y *= SC2; y.z *= SC2; y.w *= SC2;
                qf[ds] = pack8(x, y);
            }
        }

        float m_r = sink2, l_r = 1.0f;
        f32x16 O[4];
        #pragma unroll
        for (int i = 0; i < 4; ++i)
            #pragma unroll
            for (int r = 0; r < 16; ++r) O[i][r] = 0.f;

        const int nkv  = qt * 4 + 4;                 /* block tile count */
        const int nkvw = (qrow0w >> 6) + 1;          /* per-wave tile count */

        LOADT(0);
        WRITET(0);
        __syncthreads();

        int cur = 0;
        for (int t = 0; t < nkv; ++t) {
            const bool havenext = (t + 1 < nkv);
            LOADT(havenext ? t + 1 : t);             /* unconditional: hoists */
            __builtin_amdgcn_sched_barrier(0);       /* pin loads before compute */

            if (t < nkvw) {
                const u16* Kc = Ksh[cur];
                const u16* Vc = Vsh[cur];

                /* ---- S^T = K Q^T : A=K tile rows, B=Q. Lane owns q=l31. */
                f32x16 sc[2];
                #pragma unroll
                for (int kvb = 0; kvb < 2; ++kvb)
                    #pragma unroll
                    for (int r = 0; r < 16; ++r) sc[kvb][r] = 0.f;

                __builtin_amdgcn_s_setprio(1);
                #pragma unroll
                for (int kvb = 0; kvb < 2; ++kvb) {
                    const int row = kvb * 32 + l31;
                    const char* kbase = (const char*)Kc + row * 256;
                    const int sw = row & 7;
                    #pragma unroll
                    for (int ds = 0; ds < 8; ++ds) {
                        short8 kf = *(const short8*)(kbase + (((ds * 2 + hi) ^ sw) << 4));
                        sc[kvb] = __builtin_amdgcn_mfma_f32_32x32x16_bf16(
                            kf, qf[ds], sc[kvb], 0, 0, 0);
                    }
                }
                __builtin_amdgcn_s_setprio(0);

                /* ---- causal mask on the diagonal tile only */
                if (t == nkvw - 1) {
                    const int qgl = qrow0w + l31;
                    #pragma unroll
                    for (int kvb = 0; kvb < 2; ++kvb)
                        #pragma unroll
                        for (int r = 0; r < 16; ++r) {
                            const int kv = t * 64 + kvb * 32 +
                                           ((r & 3) + 8 * (r >> 2) + 4 * hi);
                            if (kv > qgl) sc[kvb][r] = -3.0e38f;
                        }
                }

                /* ---- row max: tree over lane's 32 values + one xor32 */
                float mx;
                {
                    float t8[8];
                    #pragma unroll
                    for (int i = 0; i < 8; ++i)
                        t8[i] = fmaxf(fmaxf(sc[0][i], sc[0][i + 8]),
                                      fmaxf(sc[1][i], sc[1][i + 8]));
                    const float a = fmaxf(fmaxf(t8[0], t8[4]), fmaxf(t8[1], t8[5]));
                    const float c = fmaxf(fmaxf(t8[2], t8[6]), fmaxf(t8[3], t8[7]));
                    mx = fmaxf(a, c);
                    mx = fmaxf(mx, __shfl_xor(mx, 32, 64));
                }

                /* ---- defer-max: rescale only when max grew past THR */
                if (__any(mx > m_r + THR)) {
                    const float mn = fmaxf(m_r, mx);
                    const float al = exp2f(m_r - mn);
                    m_r = mn;
                    l_r *= al;
                    #pragma unroll
                    for (int r = 0; r < 16; ++r) {
                        const float ar = __shfl(al, (r & 3) + 8 * (r >> 2) + 4 * hi, 32);
                        #pragma unroll
                        for (int db = 0; db < 4; ++db) O[db][r] *= ar;
                    }
                }

                /* ---- P = exp2(S - m): in-register, packed to bf16 pairs */
                u32 w[16];
                float rs = 0.f;
                #pragma unroll
                for (int kvb = 0; kvb < 2; ++kvb)
                    #pragma unroll
                    for (int m = 0; m < 8; ++m) {
                        const float p0 = exp2f(sc[kvb][2 * m]     - m_r);
                        const float p1 = exp2f(sc[kvb][2 * m + 1] - m_r);
                        rs += p0 + p1;
                        u32 pw;
                        asm("v_cvt_pk_bf16_f32 %0, %1, %2" : "=v"(pw) : "v"(p0), "v"(p1));
                        w[kvb * 8 + m] = pw;
                    }
                rs += __shfl_xor(rs, 32, 64);
                l_r += rs;

                u32 s[16];
                #pragma unroll
                for (int m = 0; m < 16; ++m) s[m] = __shfl_xor(w[m], 32, 64);

                /* ---- O += P V : A-frag built from w/s, B from V^T LDS */
                __builtin_amdgcn_s_setprio(1);
                #pragma unroll
                for (int k = 0; k < 4; ++k) {
                    const int b4 = ((k & 1) << 2) + ((k >> 1) << 3);
                    union { u32 u[4]; short8 v; } pa;
                    pa.u[0] = hi ? s[b4 + 2] : w[b4 + 0];
                    pa.u[1] = hi ? s[b4 + 3] : w[b4 + 1];
                    pa.u[2] = hi ? w[b4 + 2] : s[b4 + 0];
                    pa.u[3] = hi ? w[b4 + 3] : s[b4 + 1];
                    const int cidx = k * 2 + hi;
                    #pragma unroll
                    for (int db = 0; db < 4; ++db) {
                        const int d = db * 32 + l31;
                        short8 vf = *(const short8*)((const char*)Vc + d * 128 +
                                                     ((cidx ^ (d & 7)) << 4));
                        O[db] = __builtin_amdgcn_mfma_f32_32x32x16_bf16(
                            pa.v, vf, O[db], 0, 0, 0);
                    }
                }
                __builtin_amdgcn_s_setprio(0);
            }

            if (havenext) WRITET(cur ^ 1);
            __syncthreads();                         /* single barrier per tile */
            cur ^= 1;
        }

        /* ---- epilogue: normalize (l includes sink) and store fp32 */
        const float linv = 1.0f / l_r;
        #pragma unroll
        for (int r = 0; r < 16; ++r) {
            const int cr = (r & 3) + 8 * (r >> 2) + 4 * hi;
            const float lr = __shfl(linv, cr, 32);
            float* orow = og + base + (size_t)(qrow0w + cr) * HD + l31;
            #pragma unroll
            for (int db = 0; db < 4; ++db)
                orow[db * 32] = O[db][r] * lr;
        }
    }
}

/* ---------------- fallback (previous verified kernel, fp32 inputs) ------- */
__global__ __launch_bounds__(256, 3) void attn_sink_kernel(
    const float* __restrict__ qg, const float* __restrict__ kg,
    const float* __restrict__ vg, const float* __restrict__ sg,
    float* __restrict__ og)
{
    __shared__ __align__(16) u16 Ksh[KT * Dq];
    __shared__ __align__(16) u16 Vsh[Dq * KT];
    __shared__ __align__(16) u16 Psh[4][16 * KT];

    const int tid  = threadIdx.x;
    const int lane = tid & 63;
    const int wave = tid >> 6;
    const int l16  = lane & 15;
    const int quad = lane >> 4;

    const int bid = blockIdx.x;
    const int qt  = bid & 15;
    const int nch = (bid >> 4) & 3;
    const int h   = (bid >> 6) & 15;
    const int b   = bid >> 10;

    const int s0    = nch * CHUNK;
    const int qrow0 = qt * 64 + wave * 16;

    const size_t base = ((size_t)b * Sq + s0) * HD + (size_t)h * Dq;

    short8 qf[4];
    {
        const float* qrow = qg + base + (size_t)(qrow0 + l16) * HD + quad * 8;
        #pragma unroll
        for (int ks = 0; ks < 4; ++ks) {
            float4 x = *(const float4*)(qrow + ks * 32);
            float4 y = *(const float4*)(qrow + ks * 32 + 4);
            qf[ks] = pack8(x, y);
        }
    }

    const float sinkv = sg[h];

    float m_r[4], l_r[4];
    f32x4 O[8];
    #pragma unroll
    for (int i = 0; i < 8; ++i) O[i] = (f32x4){0.f, 0.f, 0.f, 0.f};
    #pragma unroll
    for (int r = 0; r < 4; ++r) { m_r[r] = sinkv; l_r[r] = 1.0f; }

    const int nkv = qt + 1;
    for (int t = 0; t < nkv; ++t) {
        const int kv0 = t * KT;
        __syncthreads();

        #pragma unroll
        for (int p = 0; p < 4; ++p) {
            int idx = tid + p * 256;
            int r = idx >> 4, c = idx & 15;
            const float* src = kg + base + (size_t)(kv0 + r) * HD + c * 8;
            float4 x = *(const float4*)src;
            float4 y = *(const float4*)(src + 4);
            *(short8*)&Ksh[(r << 7) + ((c ^ (r & 7)) << 3)] = pack8(x, y);
        }
        {
            int vr = lane;
            int c0 = wave;
            #pragma unroll
            for (int p = 0; p < 4; ++p) {
                int c = c0 + (p << 2);
                const float* src = vg + base + (size_t)(kv0 + vr) * HD + c * 8;
                float4 x = *(const float4*)src;
                float4 y = *(const float4*)(src + 4);
                float vals[8] = {x.x, x.y, x.z, x.w, y.x, y.y, y.z, y.w};
                #pragma unroll
                for (int j = 0; j < 8; ++j) {
                    int d = c * 8 + j;
                    Vsh[(d << 6) + (((vr >> 3) ^ j) << 3) + (vr & 7)] = f2bf(vals[j]);
                }
            }
        }
        __syncthreads();

        f32x4 Sv[4];
        #pragma unroll
        for (int blk = 0; blk < 4; ++blk) {
            f32x4 acc = (f32x4){0.f, 0.f, 0.f, 0.f};
            #pragma unroll
            for (int ks = 0; ks < 4; ++ks) {
                int ch = ((ks << 2) + quad) ^ (l16 & 7);
                short8 kf = *(const short8*)&Ksh[(((blk << 4) + l16) << 7) + (ch << 3)];
                acc = __builtin_amdgcn_mfma_f32_16x16x32_bf16(qf[ks], kf, acc, 0, 0, 0);
            }
            Sv[blk] = acc;
        }

        float s[4][4];
        const bool domask = (t == nkv - 1);
        #pragma unroll
        for (int blk = 0; blk < 4; ++blk) {
            #pragma unroll
            for (int r = 0; r < 4; ++r) {
                float x = Sv[blk][r] * SCALE;
                if (domask) {
                    int col = kv0 + (blk << 4) + l16;
                    int row = qrow0 + (quad << 2) + r;
                    if (col > row) x = -1.0e38f;
                }
                s[blk][r] = x;
            }
        }

        float mx[4];
        #pragma unroll
        for (int r = 0; r < 4; ++r)
            mx[r] = fmaxf(fmaxf(s[0][r], s[1][r]), fmaxf(s[2][r], s[3][r]));
        #pragma unroll
        for (int off = 1; off < 16; off <<= 1)
            #pragma unroll
            for (int r = 0; r < 4; ++r)
                mx[r] = fmaxf(mx[r], __shfl_xor(mx[r], off, 64));

        float mn[4], alpha[4], rs[4];
        #pragma unroll
        for (int r = 0; r < 4; ++r) {
            mn[r] = fmaxf(m_r[r], mx[r]);
            alpha[r] = exp2f((m_r[r] - mn[r]) * LOG2E);
            m_r[r] = mn[r];
            rs[r] = 0.f;
        }

        u16* Pw = Psh[wave];
        #pragma unroll
        for (int blk = 0; blk < 4; ++blk) {
            int colhi = (blk << 1) + (l16 >> 3);
            int collo = l16 & 7;
            #pragma unroll
            for (int r = 0; r < 4; ++r) {
                float p = exp2f((s[blk][r] - mn[r]) * LOG2E);
                rs[r] += p;
                int row = (quad << 2) + r;
                Pw[(row << 6) + ((colhi ^ (row & 7)) << 3) + collo] = f2bf(p);
            }
        }
        #pragma unroll
        for (int off = 1; off < 16; off <<= 1)
            #pragma unroll
            for (int r = 0; r < 4; ++r)
                rs[r] += __shfl_xor(rs[r], off, 64);
        #pragma unroll
        for (int r = 0; r < 4; ++r) l_r[r] = l_r[r] * alpha[r] + rs[r];

        #pragma unroll
        for (int ob = 0; ob < 8; ++ob)
            #pragma unroll
            for (int r = 0; r < 4; ++r)
                O[ob][r] *= alpha[r];

        __syncthreads();

        #pragma unroll
        for (int ks2 = 0; ks2 < 2; ++ks2) {
            int ch = ((ks2 << 2) + quad) ^ (l16 & 7);
            short8 pf = *(const short8*)&Pw[(l16 << 6) + (ch << 3)];
            #pragma unroll
            for (int ob = 0; ob < 8; ++ob) {
                int n = (ob << 4) + l16;
                short8 vf = *(const short8*)&Vsh[(n << 6) + (ch << 3)];
                O[ob] = __builtin_amdgcn_mfma_f32_16x16x32_bf16(pf, vf, O[ob], 0, 0, 0);
            }
        }
    }

    #pragma unroll
    for (int r = 0; r < 4; ++r) l_r[r] = 1.0f / l_r[r];
    #pragma unroll
    for (int ob = 0; ob < 8; ++ob) {
        #pragma unroll
        for (int r = 0; r < 4; ++r) {
            int row = qrow0 + (quad << 2) + r;
            og[base + (size_t)row * HD + (ob << 4) + l16] = O[ob][r] * l_r[r];
        }
    }
}

extern "C" void kernel_launch(void* const* d_in, const int* in_sizes, int n_in,
                              void* d_out, int out_size, void* d_ws, size_t ws_size,
                              hipStream_t stream) {
    const float* q = (const float*)d_in[0];
    const float* k = (const float*)d_in[1];
    const float* v = (const float*)d_in[2];
    const float* s = (const float*)d_in[3];
    float* out = (float*)d_out;

    if (ws_size >= WS_NEED) {
        u16* kb = (u16*)d_ws;
        u16* vt = kb + KELEMS;
        cvt_bf16_kernel<<<dim3((u32)(KELEMS / 4 / 256)), 256, 0, stream>>>(k, kb);
        vtr_kernel<<<dim3(Bq * NCH * Hq * (CHUNK / 64)), 256, 0, stream>>>(v, vt);
        /* 512 blocks: pairs (3-pi, pi) of 256-row q tiles -> uniform 20 tiles */
        attn_sink_v2<<<dim3(Bq * Hq * NCH * 2), 512, 0, stream>>>(q, kb, vt, s, out);
    } else {
        attn_sink_kernel<<<dim3(Bq * Hq * NCH * 16), 256, 0, stream>>>(
            q, k, v, s, out);
    }
}